// Round 8
// baseline (207.910 us; speedup 1.0000x reference)
//
#include <hip/hip_runtime.h>
#include <math.h>

#define HIDDEN 200
#define LOG2E 1.4426950408889634f
#define LN2   0.6931471805599453f
#define NBLK 768      // 3 blocks/CU; __launch_bounds__(256,4) guarantees co-residency
#define VBLK 1100     // virtual phase-1 blocks (550 x 2 modes)

typedef float f32x4 __attribute__((ext_vector_type(4)));

// ---------------------------------------------------------------------------
// Single fused kernel (A/B vs R5: identical math, one dispatch instead of two).
// Phase 1: build merged tables
//   EA[e][0..199]   = exp(ent[e,:] @ g_w[0:200,:])            (pre-exp'd g)
//   EA[e][200..399] =     ent[e,:] @ c_w[0:200,:]             (raw c)
//   EB[r][0..199]   = exp(rel[r,:] @ g_w[200:400,:] + tim @ g_w[400:600,:] + g_b)
//   EB[r][200..399] =     rel[r,:] @ c_w[200:400,:] + tim @ c_w[400:600,:] + c_b
// Grid barrier (device-scope atomics + threadfence; bar pre-zeroed by a
// captured hipMemsetAsync).
// Phase 2: wave-per-query softmax-combine. History copy-mask cancels under
// softmax shift-invariance (per-row constant on every logit) -> history
// arrays never read. Logits bounded (|x|<~0.5) -> no max pass.
//   out = log(eg/(2 sg) + ec/(2 sc)) = ln2*(log2(eg*sc+ec*sg) - log2(2 sg sc))
// ---------------------------------------------------------------------------
__global__ __launch_bounds__(256, 4) void fused_kernel(
    const float* __restrict__ ent, const float* __restrict__ relE,
    const float* __restrict__ tim,
    const float* __restrict__ g_w, const float* __restrict__ g_b,
    const float* __restrict__ c_w, const float* __restrict__ c_b,
    const int* __restrict__ sub, const int* __restrict__ rel,
    float* __restrict__ EA, float* __restrict__ EB,
    unsigned* __restrict__ bar, float* __restrict__ out, int N) {
  __shared__ float a0[HIDDEN], a1[HIDDEN], tl[HIDDEN];
  const int c = threadIdx.x;

  // ---------------- phase 1: tables ----------------
  for (int vb = blockIdx.x; vb < VBLK; vb += NBLK) {
    const int mode = vb / 550;  // 0 = g (exp'd), 1 = c (raw)
    const int x = vb - mode * 550;
    const float* w = mode ? c_w : g_w;
    const float* bias = mode ? c_b : g_b;
    const bool is_ent = x < 500;
    const int row0 = is_ent ? x * 2 : (x - 500) * 2;
    const float* in = is_ent ? ent : relE;
    const int k0 = is_ent ? 0 : 200;
    float* obase = (is_ent ? EA : EB) + row0 * 400 + mode * 200;

    if (c < HIDDEN) {
      a0[c] = in[row0 * HIDDEN + c];
      a1[c] = in[(row0 + 1) * HIDDEN + c];
      if (!is_ent) tl[c] = tim[c];
    }
    __syncthreads();
    if (c < HIDDEN) {
      const float* wp = w + k0 * HIDDEN + c;
      float acc0a = 0.f, acc0b = 0.f, acc1a = 0.f, acc1b = 0.f;
      #pragma unroll 4
      for (int k = 0; k < 100; ++k) {
        float w0 = wp[k * HIDDEN];
        float w1 = wp[(k + 100) * HIDDEN];
        acc0a += a0[k] * w0;
        acc0b += a0[k + 100] * w1;
        acc1a += a1[k] * w0;
        acc1b += a1[k + 100] * w1;
      }
      float r0 = acc0a + acc0b;
      float r1 = acc1a + acc1b;
      if (!is_ent) {
        const float* wt = w + 400 * HIDDEN + c;
        float ta = 0.f, tb = 0.f;
        #pragma unroll 4
        for (int k = 0; k < 100; ++k) {
          ta += tl[k] * wt[k * HIDDEN];
          tb += tl[k + 100] * wt[(k + 100) * HIDDEN];
        }
        float extra = ta + tb + bias[c];
        r0 += extra;
        r1 += extra;
      }
      if (mode == 0) {
        r0 = __builtin_amdgcn_exp2f(r0 * LOG2E);
        r1 = __builtin_amdgcn_exp2f(r1 * LOG2E);
      }
      obase[c] = r0;
      obase[400 + c] = r1;
    }
    __syncthreads();
  }

  // ---------------- grid barrier (single-use, pre-zeroed) ----------------
  __syncthreads();
  if (threadIdx.x == 0) {
    __threadfence();  // release phase-1 stores device-wide
    if (atomicAdd(&bar[0], 1u) == NBLK - 1u) {
      __threadfence();
      atomicExch(&bar[16], 1u);  // flag on a separate cache line
    } else {
      while (__hip_atomic_load(&bar[16], __ATOMIC_RELAXED,
                               __HIP_MEMORY_SCOPE_AGENT) == 0u)
        __builtin_amdgcn_s_sleep(8);
    }
    __threadfence();  // acquire
  }
  __syncthreads();

  // ---------------- phase 2: wave-per-query ----------------
  const int lane = threadIdx.x & 63;
  const bool act = lane < (HIDDEN / 4);  // 50 active lanes
  const int nwaves = NBLK * 4;
  const int w0 = blockIdx.x * 4 + (threadIdx.x >> 6);
  for (int q = w0; q < N; q += nwaves) {
    int s = __builtin_amdgcn_readfirstlane(sub[q]);
    int r = __builtin_amdgcn_readfirstlane(rel[q]);
    const f32x4* ea = (const f32x4*)(EA + s * 400);
    const f32x4* eb = (const f32x4*)(EB + r * 400);

    f32x4 eg, ec;
    float sg = 0.f, sc = 0.f;
    if (act) {
      eg = ea[lane] * eb[lane];  // exp(g-logit) from precomputed factors
      sg = (eg[0] + eg[1]) + (eg[2] + eg[3]);
      f32x4 xc = ea[lane + 50] + eb[lane + 50];
      #pragma unroll
      for (int j = 0; j < 4; ++j) {
        float e2 = __builtin_amdgcn_exp2f(xc[j] * (2.f * LOG2E));
        float th = (e2 - 1.f) * __builtin_amdgcn_rcpf(e2 + 1.f);
        ec[j] = __builtin_amdgcn_exp2f(th * LOG2E);
        sc += ec[j];
      }
    }
    #pragma unroll
    for (int m = 32; m > 0; m >>= 1) {
      sg += __shfl_xor(sg, m);
      sc += __shfl_xor(sc, m);
    }
    if (act) {
      float kl = __builtin_amdgcn_logf(2.f * sg * sc) * LN2;
      f32x4 o;
      #pragma unroll
      for (int j = 0; j < 4; ++j) {
        float num = eg[j] * sc + ec[j] * sg;
        o[j] = fmaf(__builtin_amdgcn_logf(num), LN2, -kl);
      }
      __builtin_nontemporal_store(o, (f32x4*)(out + q * HIDDEN) + lane);
    }
  }
}

// ---------------------------------------------------------------------------
extern "C" void kernel_launch(void* const* d_in, const int* in_sizes, int n_in,
                              void* d_out, int out_size, void* d_ws, size_t ws_size,
                              hipStream_t stream) {
  const float* ent  = (const float*)d_in[0];
  const float* relE = (const float*)d_in[1];
  const float* tim  = (const float*)d_in[2];
  const float* g_w  = (const float*)d_in[3];
  const float* g_b  = (const float*)d_in[4];
  const float* c_w  = (const float*)d_in[5];
  const float* c_b  = (const float*)d_in[6];
  // d_in[7..9] (history) are mathematically dead: the copy-mask is a per-row
  // constant added to every softmax logit, which cancels exactly.
  const int* sub = (const int*)d_in[10];
  const int* rel = (const int*)d_in[11];
  float* out = (float*)d_out;
  int N = in_sizes[10];

  float* ws = (float*)d_ws;
  float* EA = ws;                 // 1000 * 400
  float* EB = ws + 400000;        // 100 * 400
  unsigned* bar = (unsigned*)(ws + 448000);  // barrier counters (zeroed below)

  hipMemsetAsync((void*)bar, 0, 256, stream);  // captured; runs every replay
  fused_kernel<<<NBLK, 256, 0, stream>>>(ent, relE, tim, g_w, g_b, c_w, c_b,
                                         sub, rel, EA, EB, bar, out, N);
}

// Round 9
// 148.075 us; speedup vs baseline: 1.4041x; 1.4041x over previous
//
#include <hip/hip_runtime.h>
#include <math.h>

#define HIDDEN 200
#define LOG2E 1.4426950408889634f
#define LN2   0.6931471805599453f

typedef float f32x4 __attribute__((ext_vector_type(4)));

// ---------------------------------------------------------------------------
// Kernel A: build merged per-entity / per-relation tables.
//   EA[e][0..199]   = exp(ent[e,:] @ g_w[0:200,:])           (pre-exp'd g)
//   EA[e][200..399] =     ent[e,:] @ c_w[0:200,:]            (raw c)
//   EB[r][0..199]   = exp(rel[r,:] @ g_w[200:400,:] + tim @ g_w[400:600,:] + g_b)
//   EB[r][200..399] =     rel[r,:] @ c_w[200:400,:] + tim @ c_w[400:600,:] + c_b
// Plus EBt[col][r] transpose so pair-kernel lane access is coalesced.
// ---------------------------------------------------------------------------
__global__ __launch_bounds__(256) void table_kernel(
    const float* __restrict__ ent, const float* __restrict__ rel,
    const float* __restrict__ tim,
    const float* __restrict__ g_w, const float* __restrict__ g_b,
    const float* __restrict__ c_w, const float* __restrict__ c_b,
    float* __restrict__ EA, float* __restrict__ EB,
    float* __restrict__ EBt) {
  const int mode = blockIdx.y;  // 0 = g (exp'd), 1 = c (raw)
  const float* w = mode ? c_w : g_w;
  const float* bias = mode ? c_b : g_b;
  const bool is_ent = blockIdx.x < 500;
  const int row0 = is_ent ? blockIdx.x * 2 : (blockIdx.x - 500) * 2;
  const float* in = is_ent ? ent : rel;
  const int k0 = is_ent ? 0 : 200;

  __shared__ float a0[HIDDEN], a1[HIDDEN], tl[HIDDEN];
  const int c = threadIdx.x;
  if (c < HIDDEN) {
    a0[c] = in[row0 * HIDDEN + c];
    a1[c] = in[(row0 + 1) * HIDDEN + c];
    if (!is_ent) tl[c] = tim[c];
  }
  __syncthreads();
  if (c >= HIDDEN) return;

  const float* wp = w + k0 * HIDDEN + c;
  float acc0a = 0.f, acc0b = 0.f, acc1a = 0.f, acc1b = 0.f;
  #pragma unroll 4
  for (int k = 0; k < 100; ++k) {
    float w0 = wp[k * HIDDEN];
    float w1 = wp[(k + 100) * HIDDEN];
    acc0a += a0[k] * w0;
    acc0b += a0[k + 100] * w1;
    acc1a += a1[k] * w0;
    acc1b += a1[k + 100] * w1;
  }
  float r0 = acc0a + acc0b;
  float r1 = acc1a + acc1b;
  if (!is_ent) {
    const float* wt = w + 400 * HIDDEN + c;
    float ta = 0.f, tb = 0.f;
    #pragma unroll 4
    for (int k = 0; k < 100; ++k) {
      ta += tl[k] * wt[k * HIDDEN];
      tb += tl[k + 100] * wt[(k + 100) * HIDDEN];
    }
    float extra = ta + tb + bias[c];
    r0 += extra;
    r1 += extra;
  }
  if (mode == 0) {
    r0 = __builtin_amdgcn_exp2f(r0 * LOG2E);
    r1 = __builtin_amdgcn_exp2f(r1 * LOG2E);
  }
  const int col = mode * 200 + c;
  if (is_ent) {
    EA[row0 * 400 + col] = r0;
    EA[(row0 + 1) * 400 + col] = r1;
  } else {
    EB[row0 * 400 + col] = r0;
    EB[(row0 + 1) * 400 + col] = r1;
    EBt[col * 100 + row0] = r0;
    EBt[col * 100 + row0 + 1] = r1;
  }
}

// ---------------------------------------------------------------------------
// Kernel B: pair-denominator tables, LDS-tiled.
//   SG[s][r] = sum_k EAg[s][k]*EBg[r][k]
//   SC[s][r] = sum_k exp(tanh(Ac[s][k]+Bc[r][k]))
// 500 blocks x 256 thr: block owns 2 s-rows (staged in LDS); thread = (s
// local, r) for tid<200. EBt[k*100+r] -> consecutive lanes contiguous
// (coalesced); EBt rows are reused across both s within the block via L1.
// ~2000 waves -> latency well hidden; 200-iter chain per thread.
// ---------------------------------------------------------------------------
__global__ __launch_bounds__(256) void pair_kernel(
    const float* __restrict__ EA, const float* __restrict__ EBt,
    float* __restrict__ SG, float* __restrict__ SC) {
  const int s0 = blockIdx.x * 2;
  __shared__ float rows[2][400];  // [s][0..200)=EAg, [200..400)=Ac
  const int tid = threadIdx.x;
  for (int i = tid; i < 800; i += 256) rows[i >> 9 ? 1 : 0][i & 511] = 0.f;
  // (dummy init removed by the real staging below; keeps compiler happy)
  for (int i = tid; i < 800; i += 256) {
    int sl = i / 400, cc = i - sl * 400;
    rows[sl][cc] = EA[(s0 + sl) * 400 + cc];
  }
  __syncthreads();
  if (tid >= 200) return;
  const int sl = tid / 100;       // 0 or 1
  const int r = tid - sl * 100;   // 0..99

  const float* tg = EBt + r;            // g rows: k*100 stride
  const float* tc = EBt + 200 * 100 + r;
  const float* rg = rows[sl];
  const float* rc = rows[sl] + 200;
  float sg = 0.f, sc = 0.f;
  #pragma unroll 4
  for (int k = 0; k < 200; ++k) {
    sg = fmaf(rg[k], tg[k * 100], sg);
    float x = rc[k] + tc[k * 100];
    float e2 = __builtin_amdgcn_exp2f(x * (2.f * LOG2E));
    float th = (e2 - 1.f) * __builtin_amdgcn_rcpf(e2 + 1.f);
    sc += __builtin_amdgcn_exp2f(th * LOG2E);
  }
  SG[(s0 + sl) * 100 + r] = sg;
  SC[(s0 + sl) * 100 + r] = sc;
}

// ---------------------------------------------------------------------------
// Kernel C: fully thread-parallel query evaluation. Thread t -> query q=t/50,
// column-quad j=t%50. No cross-lane ops; 2.5M threads (full occupancy);
// stores globally contiguous f32x4. History copy-mask cancels under softmax
// shift-invariance (per-row constant on every logit) -> history arrays never
// read. Logits bounded (|x|<~0.5) -> no max pass.
//   out = log(eg/(2 SG) + ec/(2 SC))
// ---------------------------------------------------------------------------
__global__ __launch_bounds__(256) void query_kernel(
    const float* __restrict__ EA, const float* __restrict__ EB,
    const float* __restrict__ SG, const float* __restrict__ SC,
    const int* __restrict__ sub, const int* __restrict__ rel,
    float* __restrict__ out, int total) {
  int t = blockIdx.x * blockDim.x + threadIdx.x;
  if (t >= total) return;
  unsigned q = (unsigned)t / 50u;
  unsigned j = (unsigned)t - q * 50u;

  int s = sub[q];
  int r = rel[q];
  float isg = 0.5f * __builtin_amdgcn_rcpf(SG[s * 100 + r]);
  float isc = 0.5f * __builtin_amdgcn_rcpf(SC[s * 100 + r]);

  const f32x4* ea = (const f32x4*)(EA + s * 400);
  const f32x4* eb = (const f32x4*)(EB + r * 400);
  f32x4 eg = ea[j] * eb[j];
  f32x4 xc = ea[j + 50] + eb[j + 50];

  f32x4 o;
  #pragma unroll
  for (int i = 0; i < 4; ++i) {
    float e2 = __builtin_amdgcn_exp2f(xc[i] * (2.f * LOG2E));
    float th = (e2 - 1.f) * __builtin_amdgcn_rcpf(e2 + 1.f);
    float ec = __builtin_amdgcn_exp2f(th * LOG2E);
    float v = fmaf(eg[i], isg, ec * isc);
    o[i] = __builtin_amdgcn_logf(v) * LN2;
  }
  __builtin_nontemporal_store(o, (f32x4*)out + t);
}

// ---------------------------------------------------------------------------
extern "C" void kernel_launch(void* const* d_in, const int* in_sizes, int n_in,
                              void* d_out, int out_size, void* d_ws, size_t ws_size,
                              hipStream_t stream) {
  const float* ent  = (const float*)d_in[0];
  const float* relE = (const float*)d_in[1];
  const float* tim  = (const float*)d_in[2];
  const float* g_w  = (const float*)d_in[3];
  const float* g_b  = (const float*)d_in[4];
  const float* c_w  = (const float*)d_in[5];
  const float* c_b  = (const float*)d_in[6];
  // d_in[7..9] (history) are mathematically dead: the copy-mask is a per-row
  // constant added to every softmax logit, which cancels exactly.
  const int* sub = (const int*)d_in[10];
  const int* rel = (const int*)d_in[11];
  float* out = (float*)d_out;
  int N = in_sizes[10];

  float* ws = (float*)d_ws;
  float* EA  = ws;            // 1000 * 400
  float* EB  = ws + 400000;   // 100 * 400
  float* EBt = ws + 440000;   // 400 * 100
  float* SG  = ws + 480000;   // 1000 * 100
  float* SC  = ws + 580000;   // 1000 * 100

  dim3 grid1(550, 2);
  table_kernel<<<grid1, 256, 0, stream>>>(ent, relE, tim, g_w, g_b, c_w, c_b,
                                          EA, EB, EBt);
  pair_kernel<<<500, 256, 0, stream>>>(EA, EBt, SG, SC);

  int total = N * 50;  // one thread per 4 output columns
  int blocks = (total + 255) / 256;
  query_kernel<<<blocks, 256, 0, stream>>>(EA, EB, SG, SC, sub, rel, out,
                                           total);
}

// Round 12
// 126.386 us; speedup vs baseline: 1.6450x; 1.1716x over previous
//
#include <hip/hip_runtime.h>
#include <math.h>

#define HIDDEN 200
#define LOG2E 1.4426950408889634f
#define LN2   0.6931471805599453f

typedef float f32x4 __attribute__((ext_vector_type(4)));

// ---------------------------------------------------------------------------
// Kernel 1: build merged per-entity / per-relation tables.
//   EA[e][0..199]   = exp(ent[e,:] @ g_w[0:200,:])           (pre-exp'd g)
//   EA[e][200..399] =     ent[e,:] @ c_w[0:200,:]            (raw c)
//   EB[r][0..199]   = exp(rel[r,:] @ g_w[200:400,:] + tim @ g_w[400:600,:] + g_b)
//   EB[r][200..399] =     rel[r,:] @ c_w[200:400,:] + tim @ c_w[400:600,:] + c_b
// ---------------------------------------------------------------------------
__global__ __launch_bounds__(256) void precompute_kernel(
    const float* __restrict__ ent, const float* __restrict__ rel,
    const float* __restrict__ tim,
    const float* __restrict__ g_w, const float* __restrict__ g_b,
    const float* __restrict__ c_w, const float* __restrict__ c_b,
    float* __restrict__ EA, float* __restrict__ EB) {
  const int mode = blockIdx.y;  // 0 = g (exp'd), 1 = c (raw)
  const float* w = mode ? c_w : g_w;
  const float* bias = mode ? c_b : g_b;
  const bool is_ent = blockIdx.x < 500;
  const int row0 = is_ent ? blockIdx.x * 2 : (blockIdx.x - 500) * 2;
  const float* in = is_ent ? ent : rel;
  const int k0 = is_ent ? 0 : 200;
  float* obase = is_ent ? (EA + row0 * 400 + mode * 200)
                        : (EB + row0 * 400 + mode * 200);

  __shared__ float a0[HIDDEN], a1[HIDDEN], tl[HIDDEN];
  const int c = threadIdx.x;
  if (c < HIDDEN) {
    a0[c] = in[row0 * HIDDEN + c];
    a1[c] = in[(row0 + 1) * HIDDEN + c];
    if (!is_ent) tl[c] = tim[c];
  }
  __syncthreads();
  if (c >= HIDDEN) return;

  const float* wp = w + k0 * HIDDEN + c;
  float acc0a = 0.f, acc0b = 0.f, acc1a = 0.f, acc1b = 0.f;
  #pragma unroll 4
  for (int k = 0; k < 100; ++k) {
    float w0 = wp[k * HIDDEN];
    float w1 = wp[(k + 100) * HIDDEN];
    acc0a += a0[k] * w0;
    acc0b += a0[k + 100] * w1;
    acc1a += a1[k] * w0;
    acc1b += a1[k + 100] * w1;
  }
  float r0 = acc0a + acc0b;
  float r1 = acc1a + acc1b;
  if (!is_ent) {
    const float* wt = w + 400 * HIDDEN + c;
    float ta = 0.f, tb = 0.f;
    #pragma unroll 4
    for (int k = 0; k < 100; ++k) {
      ta += tl[k] * wt[k * HIDDEN];
      tb += tl[k + 100] * wt[(k + 100) * HIDDEN];
    }
    float extra = ta + tb + bias[c];
    r0 += extra;
    r1 += extra;
  }
  if (mode == 0) {
    r0 = __builtin_amdgcn_exp2f(r0 * LOG2E);
    r1 = __builtin_amdgcn_exp2f(r1 * LOG2E);
  }
  obase[c] = r0;
  obase[400 + c] = r1;
}

// ---------------------------------------------------------------------------
// Kernel 2: one 64-lane wave per query; lanes 0..49 hold 4 columns (float4).
// History copy-mask is a per-row constant on every logit -> cancels exactly
// under softmax shift-invariance (history arrays never read). Logits bounded
// (|x| < ~0.5 by construction) -> no max pass needed. g-path exps are
// precomputed: eg = EAg*EBg. Final:
//   out = log(eg/(2 sg) + ec/(2 sc)) = ln2*(log2(eg*sc + ec*sg) - log2(2 sg sc))
// ---------------------------------------------------------------------------
__global__ __launch_bounds__(256) void query_kernel(
    const float* __restrict__ EA, const float* __restrict__ EB,
    const int* __restrict__ sub, const int* __restrict__ rel,
    float* __restrict__ out, int N) {
  int gtid = blockIdx.x * blockDim.x + threadIdx.x;
  int q = gtid >> 6;
  int lane = threadIdx.x & 63;
  if (q >= N) return;

  int s = __builtin_amdgcn_readfirstlane(sub[q]);
  int r = __builtin_amdgcn_readfirstlane(rel[q]);
  bool act = lane < (HIDDEN / 4);  // 50 active lanes

  const f32x4* ea = (const f32x4*)(EA + s * 400);
  const f32x4* eb = (const f32x4*)(EB + r * 400);

  f32x4 eg, ec;
  float sg = 0.f, sc = 0.f;
  if (act) {
    eg = ea[lane] * eb[lane];  // exp(g-logit), precomputed factors
    sg = (eg[0] + eg[1]) + (eg[2] + eg[3]);
    f32x4 xc = ea[lane + 50] + eb[lane + 50];
    #pragma unroll
    for (int j = 0; j < 4; ++j) {
      float e2 = __builtin_amdgcn_exp2f(xc[j] * (2.f * LOG2E));
      float th = (e2 - 1.f) * __builtin_amdgcn_rcpf(e2 + 1.f);
      ec[j] = __builtin_amdgcn_exp2f(th * LOG2E);
      sc += ec[j];
    }
  }
  #pragma unroll
  for (int m = 32; m > 0; m >>= 1) {
    sg += __shfl_xor(sg, m);
    sc += __shfl_xor(sc, m);
  }

  if (act) {
    float kl = __builtin_amdgcn_logf(2.f * sg * sc) * LN2;  // log(2 sg sc)
    f32x4 o;
    #pragma unroll
    for (int j = 0; j < 4; ++j) {
      float num = eg[j] * sc + ec[j] * sg;
      o[j] = fmaf(__builtin_amdgcn_logf(num), LN2, -kl);
    }
    __builtin_nontemporal_store(o, (f32x4*)(out + q * HIDDEN) + lane);
  }
}

// ---------------------------------------------------------------------------
extern "C" void kernel_launch(void* const* d_in, const int* in_sizes, int n_in,
                              void* d_out, int out_size, void* d_ws, size_t ws_size,
                              hipStream_t stream) {
  const float* ent  = (const float*)d_in[0];
  const float* relE = (const float*)d_in[1];
  const float* tim  = (const float*)d_in[2];
  const float* g_w  = (const float*)d_in[3];
  const float* g_b  = (const float*)d_in[4];
  const float* c_w  = (const float*)d_in[5];
  const float* c_b  = (const float*)d_in[6];
  // d_in[7..9] (history) are mathematically dead: the copy-mask is a per-row
  // constant added to every softmax logit, which cancels exactly.
  const int* sub = (const int*)d_in[10];
  const int* rel = (const int*)d_in[11];
  float* out = (float*)d_out;
  int N = in_sizes[10];

  float* ws = (float*)d_ws;
  float* EA = ws;            // 1000 * 400
  float* EB = ws + 400000;   // 100 * 400

  dim3 grid1(550, 2);
  precompute_kernel<<<grid1, 256, 0, stream>>>(ent, relE, tim, g_w, g_b, c_w,
                                               c_b, EA, EB);

  long long threads = (long long)N * 64;
  int blocks = (int)((threads + 255) / 256);
  query_kernel<<<blocks, 256, 0, stream>>>(EA, EB, sub, rel, out, N);
}